// Round 11
// baseline (254.560 us; speedup 1.0000x reference)
//
#include <hip/hip_runtime.h>
#include <hip/hip_bf16.h>
#include <stdint.h>

#define B_   4
#define C_   256
#define CQK_ 32
#define N_   4096

typedef float f32x4  __attribute__((ext_vector_type(4)));
typedef short bf16x8 __attribute__((ext_vector_type(8)));
typedef unsigned uint4v __attribute__((ext_vector_type(4)));

__device__ __forceinline__ unsigned short f2bf(float f) {
    unsigned u = __builtin_bit_cast(unsigned, f);
    u += 0x7FFFu + ((u >> 16) & 1u);   // RNE
    return (unsigned short)(u >> 16);
}
__device__ __forceinline__ unsigned pack2(float a, float b) {
    return (unsigned)f2bf(a) | ((unsigned)f2bf(b) << 16);
}

// V fragment layout with the swapped-QK sigma permutation folded in (round-6 verified):
// elem (b,e,m): chunk = b*128 + (m>>5); within: [e>>4][ ((m>>2)&3)*16 + (e&15) ][ j ]
// with j = ((m>>4)&1)*4 + (m&3). PV B-frag (fixed chunk, eblk) is lane-linear: +l*8.
__device__ __forceinline__ size_t vfrag_off(int b, int e, int m) {
    const int j   = ((m >> 4) & 1) * 4 + (m & 3);
    const int lgp = (m >> 2) & 3;
    return (((size_t)(b * 128 + (m >> 5)) * 16 + (e >> 4)) * 64
            + (size_t)lgp * 16 + (e & 15)) * 8 + j;
}

// ---------------- pass 1: fp32 [b][c][n] -> bf16 [b][n][c] (+ W -> bf16) ----------------
__global__ __launch_bounds__(256) void transpose_kernel(
        const float* __restrict__ x, const float* __restrict__ y,
        const float* __restrict__ Wq, const float* __restrict__ Wk,
        const float* __restrict__ Wv,
        unsigned short* __restrict__ xb, unsigned short* __restrict__ yb,
        unsigned short* __restrict__ Wqb, unsigned short* __restrict__ Wkb,
        unsigned short* __restrict__ Wvb) {
    const int bid = blockIdx.x, tid = threadIdx.x;
    if (bid < 512) {
        __shared__ char lds[64 * 528];          // 64 pixel-rows x 256 bf16 (+16B pad)
        const bool isx = bid < 256;
        const int slab = bid & 255;
        const int b  = slab >> 6;
        const int n0 = (slab & 63) * 64;
        const float* __restrict__ src = isx ? x : y;
        unsigned short* __restrict__ dst = isx ? xb : yb;
        const int l = tid & 63, wv = tid >> 6;
        const float* sp = src + (size_t)(b * C_) * N_ + n0 + l;
#pragma unroll
        for (int i = 0; i < 64; i += 2) {
            const int c = wv * 64 + i;
            const float v0 = sp[(size_t)c * N_];
            const float v1 = sp[(size_t)(c + 1) * N_];
            *(unsigned*)(lds + l * 528 + c * 2) = pack2(v0, v1);
        }
        __syncthreads();
        const int n = tid >> 5, chunk = tid & 31;
#pragma unroll
        for (int j = 0; j < 8; ++j) {
            const int nn = n + j * 8;
            const uint4v v = *(const uint4v*)(lds + nn * 528 + chunk * 16);
            *(uint4v*)((char*)(dst + ((size_t)b * N_ + n0 + nn) * C_) + chunk * 16) = v;
        }
    } else {
        for (int p = (bid - 512) * 256 + tid; p < 40960; p += 64 * 256) {
            const float* s; unsigned short* d; int off;
            if (p < 4096)      { s = Wq; d = Wqb; off = p; }
            else if (p < 8192) { s = Wk; d = Wkb; off = p - 4096; }
            else               { s = Wv; d = Wvb; off = p - 8192; }
            *(unsigned*)(d + off * 2) = pack2(s[off * 2], s[off * 2 + 1]);
        }
    }
}

// ---------------- pass 2: MFMA projections, no LDS ----------------
__global__ __launch_bounds__(256) void proj_gemm(
        const unsigned short* __restrict__ xb, const unsigned short* __restrict__ yb,
        const unsigned short* __restrict__ Wqb, const unsigned short* __restrict__ Wkb,
        const unsigned short* __restrict__ Wvb,
        const float* __restrict__ bq, const float* __restrict__ bk,
        const float* __restrict__ bv,
        unsigned short* __restrict__ qf, unsigned short* __restrict__ kf,
        unsigned short* __restrict__ vf) {
    const int tid = threadIdx.x, w = tid >> 6, l = tid & 63;
    const int lr = l & 15, lg = l >> 4;
    const int gid = blockIdx.x;
    const int b  = (gid >> 1) & 3;
    const int n0 = ((((gid >> 3) << 1) | (gid & 1))) * 64;

    f32x4 accV[4][4];    // [eblk][mblk]
    f32x4 accQ[4];
#pragma unroll
    for (int e = 0; e < 4; ++e)
#pragma unroll
        for (int m = 0; m < 4; ++m) accV[e][m] = (f32x4){0.f, 0.f, 0.f, 0.f};
#pragma unroll
    for (int m = 0; m < 4; ++m) accQ[m] = (f32x4){0.f, 0.f, 0.f, 0.f};

    const unsigned short* __restrict__ Wqk = (w < 2) ? Wqb : Wkb;
    const int d0 = (w & 1) * 16;

#pragma unroll
    for (int ks = 0; ks < 8; ++ks) {
        const int c0 = ks * 32 + lg * 8;
        bf16x8 aY[4], aS[4];
#pragma unroll
        for (int mb = 0; mb < 4; ++mb)
            aY[mb] = *(const bf16x8*)(yb + ((size_t)b * N_ + n0 + mb * 16 + lr) * C_ + c0);
        if (w < 2) {
#pragma unroll
            for (int mb = 0; mb < 4; ++mb)
                aS[mb] = *(const bf16x8*)(xb + ((size_t)b * N_ + n0 + mb * 16 + lr) * C_ + c0);
        } else {
#pragma unroll
            for (int mb = 0; mb < 4; ++mb) aS[mb] = aY[mb];
        }
        bf16x8 bV[4];
#pragma unroll
        for (int eb = 0; eb < 4; ++eb)
            bV[eb] = *(const bf16x8*)(Wvb + (size_t)(w * 64 + eb * 16 + lr) * C_ + c0);
        const bf16x8 bQ = *(const bf16x8*)(Wqk + (size_t)(d0 + lr) * C_ + c0);
#pragma unroll
        for (int eb = 0; eb < 4; ++eb)
#pragma unroll
            for (int mb = 0; mb < 4; ++mb)
                accV[eb][mb] = __builtin_amdgcn_mfma_f32_16x16x32_bf16(
                    aY[mb], bV[eb], accV[eb][mb], 0, 0, 0);
#pragma unroll
        for (int mb = 0; mb < 4; ++mb)
            accQ[mb] = __builtin_amdgcn_mfma_f32_16x16x32_bf16(aS[mb], bQ, accQ[mb], 0, 0, 0);
    }

    // V epilogue: rows m = n0+mb*16+lg*4+r (r -> consecutive j slots in sigma layout)
#pragma unroll
    for (int eb = 0; eb < 4; ++eb) {
        const int e = w * 64 + eb * 16 + lr;
        const float bve = bv[e];
#pragma unroll
        for (int mb = 0; mb < 4; ++mb) {
            const size_t off = vfrag_off(b, e, n0 + mb * 16 + lg * 4);
            unsigned* p = (unsigned*)(vf + off);
            p[0] = pack2(accV[eb][mb][0] + bve, accV[eb][mb][1] + bve);
            p[1] = pack2(accV[eb][mb][2] + bve, accV[eb][mb][3] + bve);
        }
    }
    const float bqv = ((w < 2) ? bq : bk)[d0 + lr];
    unsigned short* __restrict__ dqk = (w < 2) ? qf : kf;
#pragma unroll
    for (int mb = 0; mb < 4; ++mb)
#pragma unroll
        for (int r = 0; r < 4; ++r) {
            const int n = n0 + mb * 16 + lg * 4 + r;
            dqk[((size_t)b * N_ + n) * CQK_ + d0 + lr] = f2bf(accQ[mb][r] + bqv);
        }
}

// ---------------- fused flash attention: in-register P, zero LDS ----------------
// Wave (qblk=w>>1, eh=w&1): full 128-m swapped QK for its 16 q (8 MFMA, 2x dup),
// P stays in-lane (sigma folded into vf), PV over its 128-e half (32 MFMA).
// K double-buffered in ping-pong register sets (kA/kB) — no in-place clobber of
// MFMA sources (round-8 failure suspect). Raw s_barrier keeps waves L1-coupled.
__global__ __launch_bounds__(512, 2) void attn_kernel(
        const unsigned short* __restrict__ qf, const unsigned short* __restrict__ kf,
        const unsigned short* __restrict__ vf, const float* __restrict__ x,
        const float* __restrict__ gamma, float* __restrict__ out) {
    const int tid = threadIdx.x, w = tid >> 6, l = tid & 63;
    const int lr = l & 15, lg = l >> 4;
    const int gid = blockIdx.x;
    const int b  = (gid >> 1) & 3;                       // batch -> XCD pair
    const int q0 = ((((gid >> 3) << 1) | (gid & 1))) * 64;
    const int qblk = w >> 1, eh = w & 1;

    // loop-invariant Q fragment (B-operand of swapped QK^T), own q-block only
    const bf16x8 qfr = *(const bf16x8*)(
        qf + ((size_t)b * N_ + q0 + qblk * 16 + lr) * CQK_ + lg * 8);

    f32x4 acc[8];                       // e = eh*128 + eb*16 + lr
#pragma unroll
    for (int i = 0; i < 8; ++i) acc[i] = (f32x4){0.f, 0.f, 0.f, 0.f};
    float Lacc = 0.f;

    const unsigned short* kb = kf + ((size_t)b * N_ + lr) * CQK_ + lg * 8;

#define PREFETCH_K(KT, K)                                                      \
    {                                                                          \
        const int t_ = (KT) & 31;                                              \
        _Pragma("unroll")                                                      \
        for (int mt_ = 0; mt_ < 8; ++mt_)                                      \
            K[mt_] = *(const bf16x8*)(kb + (size_t)(t_ * 128 + mt_ * 16) * CQK_); \
    }

#define BODY(KT, K)                                                            \
    {                                                                          \
        f32x4 e4_[8];                                                          \
        _Pragma("unroll")                                                      \
        for (int mt_ = 0; mt_ < 8; ++mt_)                                      \
            e4_[mt_] = __builtin_amdgcn_mfma_f32_16x16x32_bf16(                \
                K[mt_], qfr, (f32x4){0.f, 0.f, 0.f, 0.f}, 0, 0, 0);            \
        bf16x8 PA_[4];                                                         \
        _Pragma("unroll")                                                      \
        for (int ks_ = 0; ks_ < 4; ++ks_) {                                    \
            float p_[8];                                                       \
            _Pragma("unroll")                                                  \
            for (int r_ = 0; r_ < 4; ++r_) {                                   \
                p_[r_]     = __expf(e4_[2 * ks_][r_]);                         \
                p_[4 + r_] = __expf(e4_[2 * ks_ + 1][r_]);                     \
            }                                                                  \
            Lacc += ((p_[0] + p_[1]) + (p_[2] + p_[3]))                        \
                  + ((p_[4] + p_[5]) + (p_[6] + p_[7]));                       \
            uint4v pu_;                                                        \
            asm("v_cvt_pk_bf16_f32 %0, %1, %2" : "=v"(pu_[0]) : "v"(p_[0]), "v"(p_[1])); \
            asm("v_cvt_pk_bf16_f32 %0, %1, %2" : "=v"(pu_[1]) : "v"(p_[2]), "v"(p_[3])); \
            asm("v_cvt_pk_bf16_f32 %0, %1, %2" : "=v"(pu_[2]) : "v"(p_[4]), "v"(p_[5])); \
            asm("v_cvt_pk_bf16_f32 %0, %1, %2" : "=v"(pu_[3]) : "v"(p_[6]), "v"(p_[7])); \
            PA_[ks_] = __builtin_bit_cast(bf16x8, pu_);                        \
        }                                                                      \
        __builtin_amdgcn_s_setprio(1);                                         \
        _Pragma("unroll")                                                      \
        for (int ks_ = 0; ks_ < 4; ++ks_) {                                    \
            const unsigned short* vp_ =                                        \
                vf + ((size_t)(b * 128 + (KT) * 4 + ks_) * 16 + eh * 8) * 512 + l * 8; \
            _Pragma("unroll")                                                  \
            for (int eb_ = 0; eb_ < 8; ++eb_) {                                \
                const bf16x8 vbf_ = *(const bf16x8*)(vp_ + eb_ * 512);         \
                acc[eb_] = __builtin_amdgcn_mfma_f32_16x16x32_bf16(            \
                    PA_[ks_], vbf_, acc[eb_], 0, 0, 0);                        \
            }                                                                  \
        }                                                                      \
        __builtin_amdgcn_s_setprio(0);                                         \
        __builtin_amdgcn_s_barrier();                                          \
    }

    bf16x8 kA[8], kB[8];
    PREFETCH_K(0, kA);
    PREFETCH_K(1, kB);

    for (int kt = 0; kt < 32; kt += 2) {
        BODY(kt, kA);
        PREFETCH_K(kt + 2, kA);         // consumed two bodies later; no WAR window
        BODY(kt + 1, kB);
        PREFETCH_K(kt + 3, kB);
    }
#undef PREFETCH_K
#undef BODY

    // L: sum over the 4 lg-groups -> every lane holds L[q = qblk*16 + lr]
    Lacc += __shfl_xor(Lacc, 16);
    Lacc += __shfl_xor(Lacc, 32);
    float rI[4];
#pragma unroll
    for (int r = 0; r < 4; ++r) rI[r] = 1.0f / __shfl(Lacc, lg * 4 + r);

    const float g = gamma[0];
    const int nb = q0 + qblk * 16 + lg * 4;
#pragma unroll
    for (int eb = 0; eb < 8; ++eb) {
        const int e = eh * 128 + eb * 16 + lr;
        const size_t idx = ((size_t)b * C_ + e) * N_ + nb;
        const f32x4 xv = *(const f32x4*)(x + idx);
        f32x4 ov;
#pragma unroll
        for (int r = 0; r < 4; ++r)
            ov[r] = g * acc[eb][r] * rI[r] + xv[r];
        *(f32x4*)(out + idx) = ov;
    }
}

extern "C" void kernel_launch(void* const* d_in, const int* in_sizes, int n_in,
                              void* d_out, int out_size, void* d_ws, size_t ws_size,
                              hipStream_t stream) {
    (void)in_sizes; (void)n_in; (void)out_size; (void)ws_size;
    const float* x     = (const float*)d_in[0];
    const float* y     = (const float*)d_in[1];
    const float* Wq    = (const float*)d_in[2];
    const float* bq    = (const float*)d_in[3];
    const float* Wk    = (const float*)d_in[4];
    const float* bk    = (const float*)d_in[5];
    const float* Wv    = (const float*)d_in[6];
    const float* bv    = (const float*)d_in[7];
    const float* gamma = (const float*)d_in[8];
    float* out = (float*)d_out;

    unsigned short* qf  = (unsigned short*)d_ws;
    unsigned short* kf  = qf + (size_t)B_ * N_ * CQK_;
    unsigned short* vf  = kf + (size_t)B_ * N_ * CQK_;
    unsigned short* Wqb = vf + (size_t)B_ * N_ * C_;
    unsigned short* Wkb = Wqb + CQK_ * C_;
    unsigned short* Wvb = Wkb + CQK_ * C_;

    unsigned short* xb = (unsigned short*)d_out;   // dead until attn epilogue
    unsigned short* yb = xb + (size_t)B_ * N_ * C_;

    transpose_kernel<<<dim3(576), 256, 0, stream>>>(x, y, Wq, Wk, Wv, xb, yb, Wqb, Wkb, Wvb);
    proj_gemm<<<dim3(256), 256, 0, stream>>>(xb, yb, Wqb, Wkb, Wvb, bq, bk, bv, qf, kf, vf);
    attn_kernel<<<dim3(256), 512, 0, stream>>>(qf, kf, vf, x, gamma, out);
}

// Round 12
// 101.709 us; speedup vs baseline: 2.5028x; 2.5028x over previous
//
#include <hip/hip_runtime.h>
#include <hip/hip_bf16.h>
#include <stdint.h>

#define B_   4
#define C_   256
#define CQK_ 32
#define N_   4096

typedef float f32x4  __attribute__((ext_vector_type(4)));
typedef short bf16x8 __attribute__((ext_vector_type(8)));
typedef unsigned uint4v __attribute__((ext_vector_type(4)));

__device__ __forceinline__ unsigned short f2bf(float f) {
    unsigned u = __builtin_bit_cast(unsigned, f);
    u += 0x7FFFu + ((u >> 16) & 1u);   // RNE
    return (unsigned short)(u >> 16);
}
__device__ __forceinline__ unsigned pack2(float a, float b) {
    return (unsigned)f2bf(a) | ((unsigned)f2bf(b) << 16);
}

// V fragment layout (plain m-order, round-7/9/10 verified): PV B-frag is lane-linear.
// elem (b,e,m) -> [b][m>>5][e>>4][ ((m>>3)&3)*16 + (e&15) ][ m&7 ]
__device__ __forceinline__ size_t vfrag_off(int b, int e, int m) {
    return ((((size_t)b * 128 + (m >> 5)) * 16 + (e >> 4)) * 64
            + (size_t)((m >> 3) & 3) * 16 + (e & 15)) * 8 + (m & 7);
}

// ---------------- pass 1: fp32 [b][c][n] -> bf16 [b][n][c] (+ W -> bf16) ----------------
__global__ __launch_bounds__(256) void transpose_kernel(
        const float* __restrict__ x, const float* __restrict__ y,
        const float* __restrict__ Wq, const float* __restrict__ Wk,
        const float* __restrict__ Wv,
        unsigned short* __restrict__ xb, unsigned short* __restrict__ yb,
        unsigned short* __restrict__ Wqb, unsigned short* __restrict__ Wkb,
        unsigned short* __restrict__ Wvb) {
    const int bid = blockIdx.x, tid = threadIdx.x;
    if (bid < 512) {
        __shared__ char lds[64 * 528];          // 64 pixel-rows x 256 bf16 (+16B pad)
        const bool isx = bid < 256;
        const int slab = bid & 255;
        const int b  = slab >> 6;
        const int n0 = (slab & 63) * 64;
        const float* __restrict__ src = isx ? x : y;
        unsigned short* __restrict__ dst = isx ? xb : yb;
        const int l = tid & 63, wv = tid >> 6;
        const float* sp = src + (size_t)(b * C_) * N_ + n0 + l;
#pragma unroll
        for (int i = 0; i < 64; i += 2) {
            const int c = wv * 64 + i;
            const float v0 = sp[(size_t)c * N_];
            const float v1 = sp[(size_t)(c + 1) * N_];
            *(unsigned*)(lds + l * 528 + c * 2) = pack2(v0, v1);
        }
        __syncthreads();
        const int n = tid >> 5, chunk = tid & 31;
#pragma unroll
        for (int j = 0; j < 8; ++j) {
            const int nn = n + j * 8;
            const uint4v v = *(const uint4v*)(lds + nn * 528 + chunk * 16);
            *(uint4v*)((char*)(dst + ((size_t)b * N_ + n0 + nn) * C_) + chunk * 16) = v;
        }
    } else {
        for (int p = (bid - 512) * 256 + tid; p < 40960; p += 64 * 256) {
            const float* s; unsigned short* d; int off;
            if (p < 4096)      { s = Wq; d = Wqb; off = p; }
            else if (p < 8192) { s = Wk; d = Wkb; off = p - 4096; }
            else               { s = Wv; d = Wvb; off = p - 8192; }
            *(unsigned*)(d + off * 2) = pack2(s[off * 2], s[off * 2 + 1]);
        }
    }
}

// ---------------- pass 2: MFMA projections, no LDS (verified) ----------------
__global__ __launch_bounds__(256) void proj_gemm(
        const unsigned short* __restrict__ xb, const unsigned short* __restrict__ yb,
        const unsigned short* __restrict__ Wqb, const unsigned short* __restrict__ Wkb,
        const unsigned short* __restrict__ Wvb,
        const float* __restrict__ bq, const float* __restrict__ bk,
        const float* __restrict__ bv,
        unsigned short* __restrict__ qf, unsigned short* __restrict__ kf,
        unsigned short* __restrict__ vf) {
    const int tid = threadIdx.x, w = tid >> 6, l = tid & 63;
    const int lr = l & 15, lg = l >> 4;
    const int gid = blockIdx.x;
    const int b  = (gid >> 1) & 3;
    const int n0 = ((((gid >> 3) << 1) | (gid & 1))) * 64;

    f32x4 accV[4][4];    // [eblk][mblk]
    f32x4 accQ[4];
#pragma unroll
    for (int e = 0; e < 4; ++e)
#pragma unroll
        for (int m = 0; m < 4; ++m) accV[e][m] = (f32x4){0.f, 0.f, 0.f, 0.f};
#pragma unroll
    for (int m = 0; m < 4; ++m) accQ[m] = (f32x4){0.f, 0.f, 0.f, 0.f};

    const unsigned short* __restrict__ Wqk = (w < 2) ? Wqb : Wkb;
    const int d0 = (w & 1) * 16;

#pragma unroll
    for (int ks = 0; ks < 8; ++ks) {
        const int c0 = ks * 32 + lg * 8;
        bf16x8 aY[4], aS[4];
#pragma unroll
        for (int mb = 0; mb < 4; ++mb)
            aY[mb] = *(const bf16x8*)(yb + ((size_t)b * N_ + n0 + mb * 16 + lr) * C_ + c0);
        if (w < 2) {
#pragma unroll
            for (int mb = 0; mb < 4; ++mb)
                aS[mb] = *(const bf16x8*)(xb + ((size_t)b * N_ + n0 + mb * 16 + lr) * C_ + c0);
        } else {
#pragma unroll
            for (int mb = 0; mb < 4; ++mb) aS[mb] = aY[mb];
        }
        bf16x8 bV[4];
#pragma unroll
        for (int eb = 0; eb < 4; ++eb)
            bV[eb] = *(const bf16x8*)(Wvb + (size_t)(w * 64 + eb * 16 + lr) * C_ + c0);
        const bf16x8 bQ = *(const bf16x8*)(Wqk + (size_t)(d0 + lr) * C_ + c0);
#pragma unroll
        for (int eb = 0; eb < 4; ++eb)
#pragma unroll
            for (int mb = 0; mb < 4; ++mb)
                accV[eb][mb] = __builtin_amdgcn_mfma_f32_16x16x32_bf16(
                    aY[mb], bV[eb], accV[eb][mb], 0, 0, 0);
#pragma unroll
        for (int mb = 0; mb < 4; ++mb)
            accQ[mb] = __builtin_amdgcn_mfma_f32_16x16x32_bf16(aS[mb], bQ, accQ[mb], 0, 0, 0);
    }

    // V epilogue: rows m = n0+mb*16+lg*4+r (4 consecutive m -> 8B store)
#pragma unroll
    for (int eb = 0; eb < 4; ++eb) {
        const int e = w * 64 + eb * 16 + lr;
        const float bve = bv[e];
#pragma unroll
        for (int mb = 0; mb < 4; ++mb) {
            const size_t off = vfrag_off(b, e, n0 + mb * 16 + lg * 4);
            unsigned* p = (unsigned*)(vf + off);
            p[0] = pack2(accV[eb][mb][0] + bve, accV[eb][mb][1] + bve);
            p[1] = pack2(accV[eb][mb][2] + bve, accV[eb][mb][3] + bve);
        }
    }
    const float bqv = ((w < 2) ? bq : bk)[d0 + lr];
    unsigned short* __restrict__ dqk = (w < 2) ? qf : kf;
#pragma unroll
    for (int mb = 0; mb < 4; ++mb)
#pragma unroll
        for (int r = 0; r < 4; ++r) {
            const int n = n0 + mb * 16 + lg * 4 + r;
            dqk[((size_t)b * N_ + n) * CQK_ + d0 + lr] = f2bf(accQ[mb][r] + bqv);
        }
}

// ---------------- fused flash attention: TQ=64, TK=256, 8 waves, e-split PV ----------------
// r10 dataflow with two K-tiles per barrier (16 bodies, halves phase-lock overhead).
// Wave w: QK for m-blocks {w, w+8} x all 64 q; PV for e-range w*32. P via LDS
// [64q][256m] stride-528 (2-way-free rotation). V JIT-loaded in PV (no reg ping-pong).
__global__ __launch_bounds__(512, 2) void attn_kernel(
        const unsigned short* __restrict__ qf, const unsigned short* __restrict__ kf,
        const unsigned short* __restrict__ vf, const float* __restrict__ x,
        const float* __restrict__ gamma, float* __restrict__ out) {
    __shared__ char plds[2][64 * 528];  // P: [64q][256m] bf16, 528B row stride
    __shared__ float cLs[8][64];
    __shared__ float cLt[64];
    const int tid = threadIdx.x, w = tid >> 6, l = tid & 63;
    const int lr = l & 15, lg = l >> 4;
    const int gid = blockIdx.x;
    const int b  = (gid >> 1) & 3;                       // batch -> XCD pair
    const int q0 = ((((gid >> 3) << 1) | (gid & 1))) * 64;

    // loop-invariant Q fragments (B-operand of swapped QK^T)
    bf16x8 qfr[4];
#pragma unroll
    for (int qblk = 0; qblk < 4; ++qblk)
        qfr[qblk] = *(const bf16x8*)(
            qf + ((size_t)b * N_ + q0 + qblk * 16 + lr) * CQK_ + lg * 8);

    f32x4 acc[4][2];                    // [qblk][ebi] ; e = (w*2+ebi)*16 + lr
#pragma unroll
    for (int i = 0; i < 4; ++i) { acc[i][0] = (f32x4){0,0,0,0}; acc[i][1] = (f32x4){0,0,0,0}; }
    float Lacc[4] = {0.f, 0.f, 0.f, 0.f};

    const unsigned short* kbase = kf + ((size_t)b * N_ + lr) * CQK_ + lg * 8;

#define PREF_K(T, K)                                                           \
    {                                                                          \
        const int t_ = (T) & 15;                                               \
        K[0] = *(const bf16x8*)(kbase + (size_t)(t_ * 256 + w * 16) * CQK_);   \
        K[1] = *(const bf16x8*)(kbase + (size_t)(t_ * 256 + (w + 8) * 16) * CQK_); \
    }

#define HALF_QK(K, H, PW)                                                      \
    {                                                                          \
        f32x4 e4_[4];                                                          \
        _Pragma("unroll")                                                      \
        for (int qblk = 0; qblk < 4; ++qblk)                                   \
            e4_[qblk] = __builtin_amdgcn_mfma_f32_16x16x32_bf16(               \
                K[H], qfr[qblk], (f32x4){0.f, 0.f, 0.f, 0.f}, 0, 0, 0);        \
        const int mh_ = (w + (H) * 8) * 16 + lg * 4;                           \
        _Pragma("unroll")                                                      \
        for (int qblk = 0; qblk < 4; ++qblk) {                                 \
            const float p0 = __expf(e4_[qblk][0]);                             \
            const float p1 = __expf(e4_[qblk][1]);                             \
            const float p2 = __expf(e4_[qblk][2]);                             \
            const float p3 = __expf(e4_[qblk][3]);                             \
            Lacc[qblk] += (p0 + p1) + (p2 + p3);                               \
            unsigned u0, u1;                                                   \
            asm("v_cvt_pk_bf16_f32 %0, %1, %2" : "=v"(u0) : "v"(p0), "v"(p1)); \
            asm("v_cvt_pk_bf16_f32 %0, %1, %2" : "=v"(u1) : "v"(p2), "v"(p3)); \
            const int q_ = qblk * 16 + lr;                                     \
            const int byte_ = q_ * 528 + ((mh_ >> 3) << 4) + (mh_ & 7) * 2;    \
            *(unsigned long long*)((PW) + byte_) =                             \
                (unsigned long long)u0 | ((unsigned long long)u1 << 32);       \
        }                                                                      \
    }

#define BODY(T, K, KN)                                                         \
    {                                                                          \
        char* pw_ = plds[(T) & 1];                                             \
        HALF_QK(K, 0, pw_);                                                    \
        HALF_QK(K, 1, pw_);                                                    \
        asm volatile("s_waitcnt lgkmcnt(0)" ::: "memory");                     \
        __builtin_amdgcn_s_barrier();                                          \
        asm volatile("" ::: "memory");                                         \
        PREF_K((T) + 2, K);             /* consumed next-next body: no WAR */  \
        __builtin_amdgcn_s_setprio(1);                                         \
        _Pragma("unroll")                                                      \
        for (int ks_ = 0; ks_ < 8; ++ks_) {                                    \
            const unsigned short* vp_ =                                        \
                vf + ((size_t)(b * 128 + (T) * 8 + ks_) * 16) * 512;           \
            _Pragma("unroll")                                                  \
            for (int qblk = 0; qblk < 4; ++qblk) {                             \
                const int q_ = qblk * 16 + lr;                                 \
                const bf16x8 pa_ = *(const bf16x8*)(                           \
                    pw_ + q_ * 528 + ((ks_ * 4 + lg) << 4));                   \
                _Pragma("unroll")                                              \
                for (int ebi_ = 0; ebi_ < 2; ++ebi_) {                         \
                    const bf16x8 vbf_ = *(const bf16x8*)(                      \
                        vp_ + ((w * 2 + ebi_) * 64 + l) * 8);                  \
                    acc[qblk][ebi_] = __builtin_amdgcn_mfma_f32_16x16x32_bf16( \
                        pa_, vbf_, acc[qblk][ebi_], 0, 0, 0);                  \
                }                                                              \
            }                                                                  \
        }                                                                      \
        __builtin_amdgcn_s_setprio(0);                                         \
    }

    bf16x8 kA[2], kB[2];
    PREF_K(0, kA);
    PREF_K(1, kB);

    for (int t = 0; t < 16; t += 2) {
        BODY(t, kA, kAn);
        BODY(t + 1, kB, kBn);
    }
#undef PREF_K
#undef HALF_QK
#undef BODY

    // L: reduce over lg-groups, then across the 8 waves (disjoint m-block sets)
#pragma unroll
    for (int qblk = 0; qblk < 4; ++qblk) {
        Lacc[qblk] += __shfl_xor(Lacc[qblk], 16);
        Lacc[qblk] += __shfl_xor(Lacc[qblk], 32);
    }
    if (l < 16) {
#pragma unroll
        for (int qblk = 0; qblk < 4; ++qblk) cLs[w][qblk * 16 + lr] = Lacc[qblk];
    }
    __syncthreads();
    if (tid < 64) {
        float s = 0.f;
#pragma unroll
        for (int w2 = 0; w2 < 8; ++w2) s += cLs[w2][tid];
        cLt[tid] = 1.0f / s;
    }
    __syncthreads();

    const float g = gamma[0];
#pragma unroll
    for (int qblk = 0; qblk < 4; ++qblk) {
        float rI[4];
#pragma unroll
        for (int r = 0; r < 4; ++r) rI[r] = cLt[qblk * 16 + lg * 4 + r];
        const int nb = q0 + qblk * 16 + lg * 4;
#pragma unroll
        for (int ebi = 0; ebi < 2; ++ebi) {
            const int e = (w * 2 + ebi) * 16 + lr;
            const size_t idx = ((size_t)b * C_ + e) * N_ + nb;
            const f32x4 xv = *(const f32x4*)(x + idx);
            f32x4 ov;
#pragma unroll
            for (int r = 0; r < 4; ++r)
                ov[r] = g * acc[qblk][ebi][r] * rI[r] + xv[r];
            *(f32x4*)(out + idx) = ov;
        }
    }
}

extern "C" void kernel_launch(void* const* d_in, const int* in_sizes, int n_in,
                              void* d_out, int out_size, void* d_ws, size_t ws_size,
                              hipStream_t stream) {
    (void)in_sizes; (void)n_in; (void)out_size; (void)ws_size;
    const float* x     = (const float*)d_in[0];
    const float* y     = (const float*)d_in[1];
    const float* Wq    = (const float*)d_in[2];
    const float* bq    = (const float*)d_in[3];
    const float* Wk    = (const float*)d_in[4];
    const float* bk    = (const float*)d_in[5];
    const float* Wv    = (const float*)d_in[6];
    const float* bv    = (const float*)d_in[7];
    const float* gamma = (const float*)d_in[8];
    float* out = (float*)d_out;

    unsigned short* qf  = (unsigned short*)d_ws;
    unsigned short* kf  = qf + (size_t)B_ * N_ * CQK_;
    unsigned short* vf  = kf + (size_t)B_ * N_ * CQK_;
    unsigned short* Wqb = vf + (size_t)B_ * N_ * C_;
    unsigned short* Wkb = Wqb + CQK_ * C_;
    unsigned short* Wvb = Wkb + CQK_ * C_;

    unsigned short* xb = (unsigned short*)d_out;   // dead until attn epilogue
    unsigned short* yb = xb + (size_t)B_ * N_ * C_;

    transpose_kernel<<<dim3(576), 256, 0, stream>>>(x, y, Wq, Wk, Wv, xb, yb, Wqb, Wkb, Wvb);
    proj_gemm<<<dim3(256), 256, 0, stream>>>(xb, yb, Wqb, Wkb, Wvb, bq, bk, bv, qf, kf, vf);
    attn_kernel<<<dim3(256), 512, 0, stream>>>(qf, kf, vf, x, gamma, out);
}

// Round 13
// 75.818 us; speedup vs baseline: 3.3575x; 1.3415x over previous
//
#include <hip/hip_runtime.h>
#include <hip/hip_bf16.h>
#include <stdint.h>

#define B_   4
#define C_   256
#define CQK_ 32
#define N_   4096

typedef float f32x4  __attribute__((ext_vector_type(4)));
typedef short bf16x8 __attribute__((ext_vector_type(8)));
typedef unsigned uint4v __attribute__((ext_vector_type(4)));

__device__ __forceinline__ unsigned short f2bf(float f) {
    unsigned u = __builtin_bit_cast(unsigned, f);
    u += 0x7FFFu + ((u >> 16) & 1u);   // RNE
    return (unsigned short)(u >> 16);
}
__device__ __forceinline__ unsigned pack2(float a, float b) {
    return (unsigned)f2bf(a) | ((unsigned)f2bf(b) << 16);
}

// V fragment layout (plain m-order, r7/r9/r10 verified): PV B-frag is lane-linear.
// elem (b,e,m) -> [b][m>>5][e>>4][ ((m>>3)&3)*16 + (e&15) ][ m&7 ]
__device__ __forceinline__ size_t vfrag_off(int b, int e, int m) {
    return ((((size_t)b * 128 + (m >> 5)) * 16 + (e >> 4)) * 64
            + (size_t)((m >> 3) & 3) * 16 + (e & 15)) * 8 + (m & 7);
}

// ---------------- pass 1: fp32 [b][c][n] -> bf16 [b][n][c] (+ W -> bf16) ----------------
__global__ __launch_bounds__(256) void transpose_kernel(
        const float* __restrict__ x, const float* __restrict__ y,
        const float* __restrict__ Wq, const float* __restrict__ Wk,
        const float* __restrict__ Wv,
        unsigned short* __restrict__ xb, unsigned short* __restrict__ yb,
        unsigned short* __restrict__ Wqb, unsigned short* __restrict__ Wkb,
        unsigned short* __restrict__ Wvb) {
    const int bid = blockIdx.x, tid = threadIdx.x;
    if (bid < 512) {
        __shared__ char lds[64 * 528];          // 64 pixel-rows x 256 bf16 (+16B pad)
        const bool isx = bid < 256;
        const int slab = bid & 255;
        const int b  = slab >> 6;
        const int n0 = (slab & 63) * 64;
        const float* __restrict__ src = isx ? x : y;
        unsigned short* __restrict__ dst = isx ? xb : yb;
        const int l = tid & 63, wv = tid >> 6;
        const float* sp = src + (size_t)(b * C_) * N_ + n0 + l;
#pragma unroll
        for (int i = 0; i < 64; i += 2) {
            const int c = wv * 64 + i;
            const float v0 = sp[(size_t)c * N_];
            const float v1 = sp[(size_t)(c + 1) * N_];
            *(unsigned*)(lds + l * 528 + c * 2) = pack2(v0, v1);
        }
        __syncthreads();
        const int n = tid >> 5, chunk = tid & 31;
#pragma unroll
        for (int j = 0; j < 8; ++j) {
            const int nn = n + j * 8;
            const uint4v v = *(const uint4v*)(lds + nn * 528 + chunk * 16);
            *(uint4v*)((char*)(dst + ((size_t)b * N_ + n0 + nn) * C_) + chunk * 16) = v;
        }
    } else {
        for (int p = (bid - 512) * 256 + tid; p < 40960; p += 64 * 256) {
            const float* s; unsigned short* d; int off;
            if (p < 4096)      { s = Wq; d = Wqb; off = p; }
            else if (p < 8192) { s = Wk; d = Wkb; off = p - 4096; }
            else               { s = Wv; d = Wvb; off = p - 8192; }
            *(unsigned*)(d + off * 2) = pack2(s[off * 2], s[off * 2 + 1]);
        }
    }
}

// ---------------- pass 2: MFMA projections, no LDS (verified) ----------------
__global__ __launch_bounds__(256) void proj_gemm(
        const unsigned short* __restrict__ xb, const unsigned short* __restrict__ yb,
        const unsigned short* __restrict__ Wqb, const unsigned short* __restrict__ Wkb,
        const unsigned short* __restrict__ Wvb,
        const float* __restrict__ bq, const float* __restrict__ bk,
        const float* __restrict__ bv,
        unsigned short* __restrict__ qf, unsigned short* __restrict__ kf,
        unsigned short* __restrict__ vf) {
    const int tid = threadIdx.x, w = tid >> 6, l = tid & 63;
    const int lr = l & 15, lg = l >> 4;
    const int gid = blockIdx.x;
    const int b  = (gid >> 1) & 3;
    const int n0 = ((((gid >> 3) << 1) | (gid & 1))) * 64;

    f32x4 accV[4][4];    // [eblk][mblk]
    f32x4 accQ[4];
#pragma unroll
    for (int e = 0; e < 4; ++e)
#pragma unroll
        for (int m = 0; m < 4; ++m) accV[e][m] = (f32x4){0.f, 0.f, 0.f, 0.f};
#pragma unroll
    for (int m = 0; m < 4; ++m) accQ[m] = (f32x4){0.f, 0.f, 0.f, 0.f};

    const unsigned short* __restrict__ Wqk = (w < 2) ? Wqb : Wkb;
    const int d0 = (w & 1) * 16;

#pragma unroll
    for (int ks = 0; ks < 8; ++ks) {
        const int c0 = ks * 32 + lg * 8;
        bf16x8 aY[4], aS[4];
#pragma unroll
        for (int mb = 0; mb < 4; ++mb)
            aY[mb] = *(const bf16x8*)(yb + ((size_t)b * N_ + n0 + mb * 16 + lr) * C_ + c0);
        if (w < 2) {
#pragma unroll
            for (int mb = 0; mb < 4; ++mb)
                aS[mb] = *(const bf16x8*)(xb + ((size_t)b * N_ + n0 + mb * 16 + lr) * C_ + c0);
        } else {
#pragma unroll
            for (int mb = 0; mb < 4; ++mb) aS[mb] = aY[mb];
        }
        bf16x8 bV[4];
#pragma unroll
        for (int eb = 0; eb < 4; ++eb)
            bV[eb] = *(const bf16x8*)(Wvb + (size_t)(w * 64 + eb * 16 + lr) * C_ + c0);
        const bf16x8 bQ = *(const bf16x8*)(Wqk + (size_t)(d0 + lr) * C_ + c0);
#pragma unroll
        for (int eb = 0; eb < 4; ++eb)
#pragma unroll
            for (int mb = 0; mb < 4; ++mb)
                accV[eb][mb] = __builtin_amdgcn_mfma_f32_16x16x32_bf16(
                    aY[mb], bV[eb], accV[eb][mb], 0, 0, 0);
#pragma unroll
        for (int mb = 0; mb < 4; ++mb)
            accQ[mb] = __builtin_amdgcn_mfma_f32_16x16x32_bf16(aS[mb], bQ, accQ[mb], 0, 0, 0);
    }

    // V epilogue: rows m = n0+mb*16+lg*4+r (4 consecutive m -> 8B store)
#pragma unroll
    for (int eb = 0; eb < 4; ++eb) {
        const int e = w * 64 + eb * 16 + lr;
        const float bve = bv[e];
#pragma unroll
        for (int mb = 0; mb < 4; ++mb) {
            const size_t off = vfrag_off(b, e, n0 + mb * 16 + lg * 4);
            unsigned* p = (unsigned*)(vf + off);
            p[0] = pack2(accV[eb][mb][0] + bve, accV[eb][mb][1] + bve);
            p[1] = pack2(accV[eb][mb][2] + bve, accV[eb][mb][3] + bve);
        }
    }
    const float bqv = ((w < 2) ? bq : bk)[d0 + lr];
    unsigned short* __restrict__ dqk = (w < 2) ? qf : kf;
#pragma unroll
    for (int mb = 0; mb < 4; ++mb)
#pragma unroll
        for (int r = 0; r < 4; ++r) {
            const int n = n0 + mb * 16 + lg * 4 + r;
            dqk[((size_t)b * N_ + n) * CQK_ + d0 + lr] = f2bf(accQ[mb][r] + bqv);
        }
}

// ---------------- fused flash attention: TQ=64, TK=128, ks-split PV ----------------
// QK/P-write/barrier/L: verbatim r10 (m-split 8). PV: wave (eh=w>>2, ks=w&3)
// computes PARTIAL O over its m-quarter for all 64 q x its 128-e half:
// 4 P-reads/tile (each feeds 8 MFMAs), V-dup=1, V register-prefetched.
// End: 4-partial O reduction through a 64KB LDS slab, slab-distributed epilogue.
__global__ __launch_bounds__(512, 2) void attn_kernel(
        const unsigned short* __restrict__ qf, const unsigned short* __restrict__ kf,
        const unsigned short* __restrict__ vf, const float* __restrict__ x,
        const float* __restrict__ gamma, float* __restrict__ out) {
    __shared__ char plds[2][64 * 272];      // P: [64q][128m] bf16, 272B row stride
    __shared__ float oslab[2][64][128];     // O-reduction slabs (per e-half)
    __shared__ float cLs[8][64];
    __shared__ float cLt[64];
    const int tid = threadIdx.x, w = tid >> 6, l = tid & 63;
    const int lr = l & 15, lg = l >> 4;
    const int gid = blockIdx.x;
    const int b  = (gid >> 1) & 3;                       // batch -> XCD pair
    const int q0 = ((((gid >> 3) << 1) | (gid & 1))) * 64;
    const int eh = w >> 2, ksw = w & 3;

    // loop-invariant Q fragments (B-operand of swapped QK^T)
    bf16x8 qfr[4];
#pragma unroll
    for (int qblk = 0; qblk < 4; ++qblk)
        qfr[qblk] = *(const bf16x8*)(
            qf + ((size_t)b * N_ + q0 + qblk * 16 + lr) * CQK_ + lg * 8);

    f32x4 acc[4][8];                    // [qblk][ebi] partial over ksw m-quarters
#pragma unroll
    for (int i = 0; i < 4; ++i)
#pragma unroll
        for (int j = 0; j < 8; ++j) acc[i][j] = (f32x4){0.f, 0.f, 0.f, 0.f};
    float Lacc[4] = {0.f, 0.f, 0.f, 0.f};

    const unsigned short* kbase = kf + ((size_t)b * N_ + w * 16 + lr) * CQK_ + lg * 8;

#define PREF_K(T, K)                                                           \
    K = *(const bf16x8*)(kbase + (size_t)(((T) & 31) * 128) * CQK_);

#define PREF_V(T)                                                              \
    {                                                                          \
        const int t_ = (T) & 31;                                               \
        _Pragma("unroll")                                                      \
        for (int ebi_ = 0; ebi_ < 8; ++ebi_)                                   \
            vV[ebi_] = *(const bf16x8*)(                                       \
                vf + ((size_t)((b * 128 + t_ * 4 + ksw) * 16 + eh * 8 + ebi_)) \
                         * 512 + l * 8);                                       \
    }

#define BODY(T, K)                                                             \
    {                                                                          \
        f32x4 e4_[4];                                                          \
        _Pragma("unroll")                                                      \
        for (int qblk = 0; qblk < 4; ++qblk)                                   \
            e4_[qblk] = __builtin_amdgcn_mfma_f32_16x16x32_bf16(               \
                K, qfr[qblk], (f32x4){0.f, 0.f, 0.f, 0.f}, 0, 0, 0);           \
        char* pw_ = plds[(T) & 1];                                             \
        const int m2_ = w * 16 + lg * 4;                                       \
        _Pragma("unroll")                                                      \
        for (int qblk = 0; qblk < 4; ++qblk) {                                 \
            const float p0 = __expf(e4_[qblk][0]);                             \
            const float p1 = __expf(e4_[qblk][1]);                             \
            const float p2 = __expf(e4_[qblk][2]);                             \
            const float p3 = __expf(e4_[qblk][3]);                             \
            Lacc[qblk] += (p0 + p1) + (p2 + p3);                               \
            unsigned u0, u1;                                                   \
            asm("v_cvt_pk_bf16_f32 %0, %1, %2" : "=v"(u0) : "v"(p0), "v"(p1)); \
            asm("v_cvt_pk_bf16_f32 %0, %1, %2" : "=v"(u1) : "v"(p2), "v"(p3)); \
            const int q_ = qblk * 16 + lr;                                     \
            const int byte_ = q_ * 272 + ((m2_ >> 3) << 4) + (m2_ & 7) * 2;    \
            *(unsigned long long*)(pw_ + byte_) =                              \
                (unsigned long long)u0 | ((unsigned long long)u1 << 32);       \
        }                                                                      \
        asm volatile("s_waitcnt lgkmcnt(0)" ::: "memory");                     \
        __builtin_amdgcn_s_barrier();                                          \
        asm volatile("" ::: "memory");                                         \
        PREF_K((T) + 2, K);                                                    \
        __builtin_amdgcn_s_setprio(1);                                         \
        _Pragma("unroll")                                                      \
        for (int qblk = 0; qblk < 4; ++qblk) {                                 \
            const int q_ = qblk * 16 + lr;                                     \
            const bf16x8 pa_ = *(const bf16x8*)(                               \
                pw_ + q_ * 272 + ((ksw * 4 + lg) << 4));                       \
            _Pragma("unroll")                                                  \
            for (int ebi_ = 0; ebi_ < 8; ++ebi_)                               \
                acc[qblk][ebi_] = __builtin_amdgcn_mfma_f32_16x16x32_bf16(     \
                    pa_, vV[ebi_], acc[qblk][ebi_], 0, 0, 0);                  \
        }                                                                      \
        __builtin_amdgcn_s_setprio(0);                                         \
        PREF_V((T) + 1);                /* consumed next body after QK+exp */  \
    }

    bf16x8 kA, kB, vV[8];
    PREF_K(0, kA);
    PREF_K(1, kB);
    PREF_V(0);

    for (int kt = 0; kt < 32; kt += 2) {
        BODY(kt, kA);
        BODY(kt + 1, kB);
    }
#undef PREF_K
#undef PREF_V
#undef BODY

    // ---- L reduction (verbatim r10: QK m-split is unchanged) ----
#pragma unroll
    for (int qblk = 0; qblk < 4; ++qblk) {
        Lacc[qblk] += __shfl_xor(Lacc[qblk], 16);
        Lacc[qblk] += __shfl_xor(Lacc[qblk], 32);
    }
    if (l < 16) {
#pragma unroll
        for (int qblk = 0; qblk < 4; ++qblk) cLs[w][qblk * 16 + lr] = Lacc[qblk];
    }
    __syncthreads();
    if (tid < 64) {
        float s = 0.f;
#pragma unroll
        for (int w2 = 0; w2 < 8; ++w2) s += cLs[w2][tid];
        cLt[tid] = 1.0f / s;
    }
    __syncthreads();

    // ---- O reduction: chain ksw 3 -> 2 -> 1 -> 0 through oslab[eh] ----
#pragma unroll
    for (int round = 3; round > 0; --round) {
        if (ksw == round) {
#pragma unroll
            for (int qblk = 0; qblk < 4; ++qblk)
#pragma unroll
                for (int ebi = 0; ebi < 8; ++ebi)
#pragma unroll
                    for (int r = 0; r < 4; ++r)
                        oslab[eh][qblk * 16 + lg * 4 + r][ebi * 16 + lr] = acc[qblk][ebi][r];
        }
        __syncthreads();
        if (ksw == round - 1) {
#pragma unroll
            for (int qblk = 0; qblk < 4; ++qblk)
#pragma unroll
                for (int ebi = 0; ebi < 8; ++ebi)
#pragma unroll
                    for (int r = 0; r < 4; ++r)
                        acc[qblk][ebi][r] += oslab[eh][qblk * 16 + lg * 4 + r][ebi * 16 + lr];
        }
        __syncthreads();
    }
    // ksw==0 waves hold the full sums; publish for the distributed epilogue
    if (ksw == 0) {
#pragma unroll
        for (int qblk = 0; qblk < 4; ++qblk)
#pragma unroll
            for (int ebi = 0; ebi < 8; ++ebi)
#pragma unroll
                for (int r = 0; r < 4; ++r)
                    oslab[eh][qblk * 16 + lg * 4 + r][ebi * 16 + lr] = acc[qblk][ebi][r];
    }
    __syncthreads();

    // ---- epilogue: each wave stores its r10-style e-slice ----
    const float g = gamma[0];
#pragma unroll
    for (int qblk = 0; qblk < 4; ++qblk) {
        float rI[4];
#pragma unroll
        for (int r = 0; r < 4; ++r) rI[r] = cLt[qblk * 16 + lg * 4 + r];
        const int nb = q0 + qblk * 16 + lg * 4;
#pragma unroll
        for (int ebi = 0; ebi < 2; ++ebi) {
            const int e = (w * 2 + ebi) * 16 + lr;
            const size_t idx = ((size_t)b * C_ + e) * N_ + nb;
            const f32x4 xv = *(const f32x4*)(x + idx);
            f32x4 ov;
#pragma unroll
            for (int r = 0; r < 4; ++r) {
                const float val = oslab[e >> 7][qblk * 16 + lg * 4 + r][e & 127];
                ov[r] = g * val * rI[r] + xv[r];
            }
            *(f32x4*)(out + idx) = ov;
        }
    }
}

extern "C" void kernel_launch(void* const* d_in, const int* in_sizes, int n_in,
                              void* d_out, int out_size, void* d_ws, size_t ws_size,
                              hipStream_t stream) {
    (void)in_sizes; (void)n_in; (void)out_size; (void)ws_size;
    const float* x     = (const float*)d_in[0];
    const float* y     = (const float*)d_in[1];
    const float* Wq    = (const float*)d_in[2];
    const float* bq    = (const float*)d_in[3];
    const float* Wk    = (const float*)d_in[4];
    const float* bk    = (const float*)d_in[5];
    const float* Wv    = (const float*)d_in[6];
    const float* bv    = (const float*)d_in[7];
    const float* gamma = (const float*)d_in[8];
    float* out = (float*)d_out;

    unsigned short* qf  = (unsigned short*)d_ws;
    unsigned short* kf  = qf + (size_t)B_ * N_ * CQK_;
    unsigned short* vf  = kf + (size_t)B_ * N_ * CQK_;
    unsigned short* Wqb = vf + (size_t)B_ * N_ * C_;
    unsigned short* Wkb = Wqb + CQK_ * C_;
    unsigned short* Wvb = Wkb + CQK_ * C_;

    unsigned short* xb = (unsigned short*)d_out;   // dead until attn epilogue
    unsigned short* yb = xb + (size_t)B_ * N_ * C_;

    transpose_kernel<<<dim3(576), 256, 0, stream>>>(x, y, Wq, Wk, Wv, xb, yb, Wqb, Wkb, Wvb);
    proj_gemm<<<dim3(256), 256, 0, stream>>>(xb, yb, Wqb, Wkb, Wvb, bq, bk, bv, qf, kf, vf);
    attn_kernel<<<dim3(256), 512, 0, stream>>>(qf, kf, vf, x, gamma, out);
}